// Round 6
// baseline (3092.654 us; speedup 1.0000x reference)
//
#include <hip/hip_runtime.h>
#include <stdint.h>

#define NTOK  32000
#define NINP  512
#define NHID  1024
#define NBATCH 64
#define NTIME 512
#define NGATE 4096
#define H3    341   // NHID/3

typedef __attribute__((ext_vector_type(8))) short  short8;
typedef __attribute__((ext_vector_type(4))) float  floatx4;
typedef unsigned long long ull;

#define HBUF_DW (NBATCH * NHID / 2)  // 32768 dwords per h buffer

__device__ __forceinline__ unsigned short f2bf(float f) {
  union { float f; unsigned u; } v; v.f = f;
  unsigned r = v.u + 0x7fffu + ((v.u >> 16) & 1u);
  return (unsigned short)(r >> 16);
}
__device__ __forceinline__ float bf2f(unsigned short h) {
  union { unsigned u; float f; } v; v.u = ((unsigned)h) << 16;
  return v.f;
}

// packed col p -> original gate row g = q*NHID + u
// p = cb*128 + w*32 + uu*4 + q ; u = cb*32 + w*8 + uu
__device__ __forceinline__ int pack2gate(int p) {
  int cb = p >> 7, r7 = p & 127;
  int w = r7 >> 5, r5 = r7 & 31;
  int uu = r5 >> 2, q = r5 & 3;
  int u = cb * 32 + w * 8 + uu;
  return q * NHID + u;
}

// ---------------- prep kernels ----------------

__global__ void k_pack_w(const float* __restrict__ src, unsigned short* __restrict__ dst, int K) {
  int p = blockIdx.x;
  int g = pack2gate(p);
  const float* s = src + (size_t)g * K;
  unsigned short* d = dst + (size_t)p * K;
  for (int k = threadIdx.x * 2; k < K; k += 512) {
    d[k] = f2bf(s[k]);
    d[k + 1] = f2bf(s[k + 1]);
  }
}

__global__ void k_bias(const float* __restrict__ bih, const float* __restrict__ bhh,
                       float* __restrict__ bp) {
  int p = blockIdx.x * 256 + threadIdx.x;
  if (p < NGATE) { int g = pack2gate(p); bp[p] = bih[g] + bhh[g]; }
}

// init all 3 tagged h buffers:
// buf0 = hx tagged 0 (t=0 expects tag 0); buf1 scrub tag0 (t=1 expects 1);
// buf2 scrub tag1 (t=2 expects 0). Rewritten every launch (graph replay safety).
__global__ void k_hbuf(const float* __restrict__ hx, unsigned* __restrict__ hb) {
  int i = blockIdx.x * 256 + threadIdx.x;  // 0 .. 3*HBUF_DW-1
  int buf = i >> 15;
  int d = i & (HBUF_DW - 1);
  unsigned v;
  if (buf == 0) {
    v = (unsigned)f2bf(hx[2 * d]) | ((unsigned)f2bf(hx[2 * d + 1]) << 16);
    v &= ~(1u << 16);  // tag 0
  } else if (buf == 1) {
    v = 0u;             // tag 0 != expected 1
  } else {
    v = 0x00010000u;    // tag 1 != expected 0
  }
  hb[buf * HBUF_DW + d] = v;
}

// gather embeddings for one chunk: Ag[row][k] bf16, row = tl*64 + b
__global__ void k_gather(const int* __restrict__ input, const float* __restrict__ emb,
                         unsigned short* __restrict__ Ag, int t0, int Tc) {
  int total = Tc * 64 * (NINP / 8);
  for (int ci = blockIdx.x * 256 + threadIdx.x; ci < total; ci += gridDim.x * 256) {
    int row = ci >> 6;
    int k8 = (ci & 63) * 8;
    int b = row & 63;
    int tl = row >> 6;
    int tok = input[(size_t)b * NTIME + t0 + tl];
    const float* s = emb + (size_t)tok * NINP + k8;
    unsigned short* d = Ag + (size_t)row * NINP + k8;
#pragma unroll
    for (int j = 0; j < 8; ++j) d[j] = f2bf(s[j]);
  }
}

// ---------------- x_proj GEMM: [M,512] x [4096,512]^T -> bf16 [M,4096] (+bias) ----------------

__global__ __launch_bounds__(256) void k_gemm(const unsigned short* __restrict__ Ag,
                                              const unsigned short* __restrict__ Wp,
                                              const float* __restrict__ biasP,
                                              unsigned short* __restrict__ xproj, int M) {
  __shared__ __attribute__((aligned(16))) unsigned short As[128 * 64];
  __shared__ __attribute__((aligned(16))) unsigned short Bs[128 * 64];
  const int tid = threadIdx.x;
  const int lane = tid & 63;
  const int w = tid >> 6;
  const int wr = w >> 1, wc = w & 1;
  const size_t rowbase = (size_t)blockIdx.x * 128;
  const int pbase = blockIdx.y * 128;

  floatx4 z = {0.f, 0.f, 0.f, 0.f};
  floatx4 acc[4][4];
#pragma unroll
  for (int i = 0; i < 4; ++i)
#pragma unroll
    for (int j = 0; j < 4; ++j) acc[i][j] = z;

  for (int kk = 0; kk < NINP; kk += 64) {
    // stage 128x64 bf16 tiles (XOR-swizzled rows: byte ^= (row&7)<<4)
#pragma unroll
    for (int j = 0; j < 4; ++j) {
      int ci = j * 256 + tid;
      int r = ci >> 3;
      int kb = (ci & 7) * 16;
      int dst = r * 128 + (kb ^ ((r & 7) << 4));
      *(short8*)((char*)As + dst) =
          *(const short8*)((const char*)Ag + ((rowbase + r) * NINP + kk) * 2 + kb);
      *(short8*)((char*)Bs + dst) =
          *(const short8*)((const char*)Wp + ((size_t)(pbase + r) * NINP + kk) * 2 + kb);
    }
    __syncthreads();
#pragma unroll
    for (int k32 = 0; k32 < 2; ++k32) {
      short8 af[4], bfr[4];
      int kq = k32 * 64 + (lane >> 4) * 16;
#pragma unroll
      for (int t = 0; t < 4; ++t) {
        int r = wr * 64 + t * 16 + (lane & 15);
        af[t] = *(const short8*)((const char*)As + r * 128 + (kq ^ ((r & 7) << 4)));
        int cc = wc * 64 + t * 16 + (lane & 15);
        bfr[t] = *(const short8*)((const char*)Bs + cc * 128 + (kq ^ ((cc & 7) << 4)));
      }
#pragma unroll
      for (int tm = 0; tm < 4; ++tm)
#pragma unroll
        for (int tn = 0; tn < 4; ++tn)
          acc[tm][tn] = __builtin_amdgcn_mfma_f32_16x16x32_bf16(af[tm], bfr[tn], acc[tm][tn], 0, 0, 0);
    }
    __syncthreads();
  }
  // epilogue: D row=(lane>>4)*4+j, col=lane&15  (guide-verified layout)
#pragma unroll
  for (int tn = 0; tn < 4; ++tn) {
    int p = pbase + wc * 64 + tn * 16 + (lane & 15);
    float bv = biasP[p];
#pragma unroll
    for (int tm = 0; tm < 4; ++tm) {
      size_t r0 = rowbase + wr * 64 + tm * 16 + ((lane >> 4) * 4);
#pragma unroll
      for (int j = 0; j < 4; ++j)
        xproj[(r0 + j) * NGATE + p] = f2bf(acc[tm][tn][j] + bv);
    }
  }
}

// ---------------- persistent LSTM recurrence ----------------
// 256 blocks x 256 thr. block: rg = bid&7 (8-row batch group), cb = bid>>3 (128 packed cols).
// Weights register-resident. Sync: h-words are self-announcing — LSB of the odd
// bf16 in each packed dword carries epoch parity; consumers poll the data itself.
// 3 rotating h buffers make {h(t), h(t-3)} the only possible slot contents at
// epoch t, and their tags differ. Single L3 crossing per step.

__global__ __launch_bounds__(256, 1) void k_rec(const unsigned short* __restrict__ Whp,
                                                const unsigned short* __restrict__ xproj,
                                                unsigned* __restrict__ hbuf,
                                                float* __restrict__ cbuf,
                                                float* __restrict__ featbuf,
                                                const float* __restrict__ cx_in,
                                                const int* __restrict__ seq_len,
                                                float* __restrict__ out,
                                                int t0, int Tc) {
  __shared__ __attribute__((aligned(16))) unsigned short hs[16 * NHID];  // 32KB swizzled
  __shared__ __attribute__((aligned(16))) unsigned short xs[8 * 128];    // 2KB
  __shared__ __attribute__((aligned(16))) float gs[4][32][8];            // 4KB

  const int tid = threadIdx.x;
  const int lane = tid & 63;
  const int w = tid >> 6;
  const int rg = blockIdx.x & 7;
  const int cb = blockIdx.x >> 3;
  const int colbase = cb * 128 + w * 32;

  // zero the pad rows 8..15 of hs once (never rewritten)
  {
    short8 zz = {0, 0, 0, 0, 0, 0, 0, 0};
    short8* zp = (short8*)(hs + 8 * NHID);
    for (int i = tid; i < 1024; i += 256) zp[i] = zz;
  }

  // persistent weight fragments: wave covers 32 packed cols, full K=1024
  short8 wf[64];
  {
    const int c0 = lane & 15;
    const int ke = (lane >> 4) * 8;
#pragma unroll
    for (int i = 0; i < 64; ++i) {
      int kk = i >> 1, n = i & 1;
      wf[i] = *(const short8*)(Whp + (size_t)(colbase + n * 16 + c0) * NHID + kk * 32 + ke);
    }
  }

  const int urow = lane >> 3;  // 0..7
  const int uu = lane & 7;     // 0..7
  const int row_g = rg * 8 + urow;
  const int u_g = cb * 32 + w * 8 + uu;
  float c = (t0 == 0) ? cx_in[row_g * NHID + u_g] : cbuf[row_g * NHID + u_g];
  float feat = (t0 == 0) ? 0.f : featbuf[row_g * NHID + u_g];
  const int sl = seq_len[row_g];

  // prefetch xproj slice for tl=0 into regs (stager: tid<128)
  short8 xreg;
  if (tid < 128) {
    int r = tid >> 4;
    int kb = (tid & 15) * 16;
    xreg = *(const short8*)((const char*)xproj +
                            ((size_t)(0 * 64 + rg * 8 + r) * NGATE + cb * 128) * 2 + kb);
  }

  for (int tl = 0; tl < Tc; ++tl) {
    const int tglob = t0 + tl;
    const unsigned rtag = (unsigned)(tglob & 1);
    // row offset computed in DWORD units on the unsigned* base, THEN cast to ull*
    // (round-5 bug: dword-unit offset applied to a ull* read 2x too far -> deadlock)
    const ull* hsrc =
        (const ull*)(hbuf + (size_t)(tglob % 3) * HBUF_DW + (size_t)rg * 8 * (NHID / 2));

    __syncthreads();  // hs safe to overwrite (prev MFMA reads done)

    // write current step's x slice (prefetched last iter) into LDS
    if (tid < 128) {
      int r = tid >> 4;
      int kb = (tid & 15) * 16;
      *(short8*)((char*)xs + r * 256 + kb) = xreg;
    }

    // stage h (8 rows x 1024 bf16, 16KB): tag-poll 8B words -> swizzled LDS.
    // issue all 8 loads first (pipelined), then validate+write, re-polling stragglers.
    {
      ull vv[8];
#pragma unroll
      for (int j = 0; j < 8; ++j)
        vv[j] = __hip_atomic_load(hsrc + j * 256 + tid, __ATOMIC_RELAXED,
                                  __HIP_MEMORY_SCOPE_AGENT);
#pragma unroll
      for (int j = 0; j < 8; ++j) {
        ull v = vv[j];
        while ((((v >> 16) ^ rtag) | ((v >> 48) ^ rtag)) & 1ull) {
          __builtin_amdgcn_s_sleep(1);
          v = __hip_atomic_load(hsrc + j * 256 + tid, __ATOMIC_RELAXED,
                                __HIP_MEMORY_SCOPE_AGENT);
        }
        int ci = j * 256 + tid;   // 8B-unit index, 0..2047
        int r = ci >> 8;          // row 0..7
        int kb8 = (ci & 255) * 8; // byte offset in row
        *(ull*)((char*)hs + r * 2048 + (kb8 ^ ((r & 7) << 4))) = v;
      }
    }
    __syncthreads();

    // prefetch next step's x slice (independent; hides under MFMA)
    if (tid < 128 && tl + 1 < Tc) {
      int r = tid >> 4;
      int kb = (tid & 15) * 16;
      xreg = *(const short8*)((const char*)xproj +
                              ((size_t)((tl + 1) * 64 + rg * 8 + r) * NGATE + cb * 128) * 2 + kb);
    }

    // gates[16(8 valid) x 32] = h @ Whp^T, fp32 accum, 4-acc interleave
    floatx4 acc0a = {0.f, 0.f, 0.f, 0.f}, acc0b = {0.f, 0.f, 0.f, 0.f};
    floatx4 acc1a = {0.f, 0.f, 0.f, 0.f}, acc1b = {0.f, 0.f, 0.f, 0.f};
    {
      const int rr = lane & 15;
      const int kq = (lane >> 4) * 16;
#pragma unroll
      for (int kk = 0; kk < 32; kk += 2) {
        int kb0 = kk * 64 + kq;
        int kb1 = (kk + 1) * 64 + kq;
        short8 a0 = *(const short8*)((const char*)hs + rr * 2048 + (kb0 ^ ((rr & 7) << 4)));
        short8 a1 = *(const short8*)((const char*)hs + rr * 2048 + (kb1 ^ ((rr & 7) << 4)));
        acc0a = __builtin_amdgcn_mfma_f32_16x16x32_bf16(a0, wf[2 * kk + 0], acc0a, 0, 0, 0);
        acc1a = __builtin_amdgcn_mfma_f32_16x16x32_bf16(a0, wf[2 * kk + 1], acc1a, 0, 0, 0);
        acc0b = __builtin_amdgcn_mfma_f32_16x16x32_bf16(a1, wf[2 * kk + 2], acc0b, 0, 0, 0);
        acc1b = __builtin_amdgcn_mfma_f32_16x16x32_bf16(a1, wf[2 * kk + 3], acc1b, 0, 0, 0);
      }
    }
    floatx4 acc0 = acc0a + acc0b;
    floatx4 acc1 = acc1a + acc1b;

    // add x_proj, dump gates to per-wave LDS (valid lanes: rows 0..7)
    if (lane < 32) {
      int r0 = (lane >> 4) * 4;
      int c0 = lane & 15;
      floatx4 g0, g1;
#pragma unroll
      for (int j = 0; j < 4; ++j) {
        g0[j] = acc0[j] + bf2f(xs[(r0 + j) * 128 + w * 32 + c0]);
        g1[j] = acc1[j] + bf2f(xs[(r0 + j) * 128 + w * 32 + c0 + 16]);
      }
      *(floatx4*)&gs[w][c0][r0] = g0;
      *(floatx4*)&gs[w][c0 + 16][r0] = g1;
    }
    // same-wave in-order DS: reads below see writes above

    // LSTM update: one (row,unit) per lane
    float gi = gs[w][uu * 4 + 0][urow];
    float gf = gs[w][uu * 4 + 1][urow];
    float gg = gs[w][uu * 4 + 2][urow];
    float go = gs[w][uu * 4 + 3][urow];
    float si = 1.f / (1.f + __expf(-gi));
    float sf = 1.f / (1.f + __expf(-gf));
    float tg = tanhf(gg);
    float so = 1.f / (1.f + __expf(-go));
    c = sf * c + si * tg;
    float h = so * tanhf(c);
    if (tglob < sl) feat += h;

    // paired-lane packed h store, epoch tag in bit16 (odd h's bf16 LSB),
    // relaxed agent atomic — fire-and-forget, no drain.
    {
      unsigned hb = (unsigned)f2bf(h);
      unsigned partner = (unsigned)__shfl_xor((int)hb, 1);
      if ((lane & 1) == 0) {
        unsigned packed = hb | (partner << 16);
        packed = (packed & ~(1u << 16)) | ((unsigned)((tglob + 1) & 1) << 16);
        unsigned* dst = hbuf + (size_t)((tglob + 1) % 3) * HBUF_DW +
                        ((row_g * NHID + u_g) >> 1);
        __hip_atomic_store(dst, packed, __ATOMIC_RELAXED, __HIP_MEMORY_SCOPE_AGENT);
      }
    }
    if (tglob == NTIME - 1) out[128 + row_g * NHID + u_g] = h;
  }

  cbuf[row_g * NHID + u_g] = c;
  featbuf[row_g * NHID + u_g] = feat;
  if (t0 + Tc == NTIME) out[128 + NBATCH * NHID + row_g * NHID + u_g] = c;
}

// ---------------- final FCs + log_softmax ----------------

__global__ void k_fc(const float* __restrict__ feat, const int* __restrict__ seq_len,
                     const float* __restrict__ w1, const float* __restrict__ b1,
                     const float* __restrict__ w2, const float* __restrict__ b2,
                     float* __restrict__ out) {
  int b = blockIdx.x;
  int tid = threadIdx.x;
  __shared__ float fs[NHID];
  __shared__ float x1s[H3 + 3];
  float inv = 1.f / (float)seq_len[b];
  for (int i = tid; i < NHID; i += 256) fs[i] = feat[(size_t)b * NHID + i] * inv;
  __syncthreads();
  for (int j = tid; j < H3; j += 256) {
    const float* wr = w1 + (size_t)j * NHID;
    float s = b1[j];
    for (int k = 0; k < NHID; k += 4)
      s += fs[k] * wr[k] + fs[k + 1] * wr[k + 1] + fs[k + 2] * wr[k + 2] + fs[k + 3] * wr[k + 3];
    x1s[j] = s;
  }
  __syncthreads();
  if (tid == 0) {
    float l0 = b2[0], l1 = b2[1];
    for (int k = 0; k < H3; ++k) {
      l0 += w2[k] * x1s[k];
      l1 += w2[H3 + k] * x1s[k];
    }
    float m = fmaxf(l0, l1);
    float lse = m + logf(__expf(l0 - m) + __expf(l1 - m));
    out[b * 2 + 0] = l0 - lse;
    out[b * 2 + 1] = l1 - lse;
  }
}

// ---------------- host ----------------

extern "C" void kernel_launch(void* const* d_in, const int* in_sizes, int n_in, void* d_out,
                              int out_size, void* d_ws, size_t ws_size, hipStream_t stream) {
  const int* input = (const int*)d_in[0];
  const float* hx = (const float*)d_in[1];
  const float* cx = (const float*)d_in[2];
  const int* seq_len = (const int*)d_in[3];
  const float* emb = (const float*)d_in[4];
  const float* W_ih = (const float*)d_in[5];
  const float* W_hh = (const float*)d_in[6];
  const float* b_ih = (const float*)d_in[7];
  const float* b_hh = (const float*)d_in[8];
  const float* fc1W = (const float*)d_in[9];
  const float* fc1b = (const float*)d_in[10];
  const float* fc2W = (const float*)d_in[11];
  const float* fc2b = (const float*)d_in[12];
  float* out = (float*)d_out;

  char* ws = (char*)d_ws;
  size_t off = 0;
  auto take = [&](size_t n) {
    char* p = ws + off;
    off = (off + n + 255) & ~(size_t)255;
    return p;
  };
  unsigned short* WihP = (unsigned short*)take((size_t)NGATE * NINP * 2);
  unsigned short* WhhP = (unsigned short*)take((size_t)NGATE * NHID * 2);
  float* biasP = (float*)take(NGATE * 4);
  unsigned* hbuf = (unsigned*)take((size_t)3 * HBUF_DW * 4);
  float* cbuf = (float*)take((size_t)NBATCH * NHID * 4);
  float* featbuf = (float*)take((size_t)NBATCH * NHID * 4);
  size_t fixed = off;

  int Tc = 512;
  while (Tc > 8) {
    size_t need = fixed + ((size_t)Tc * 64 * NINP * 2 + 256) + ((size_t)Tc * 64 * NGATE * 2 + 256);
    if (need <= ws_size) break;
    Tc >>= 1;
  }
  unsigned short* Ag = (unsigned short*)take((size_t)Tc * 64 * NINP * 2);
  unsigned short* xproj = (unsigned short*)take((size_t)Tc * 64 * NGATE * 2);

  k_pack_w<<<NGATE, 256, 0, stream>>>(W_ih, WihP, NINP);
  k_pack_w<<<NGATE, 256, 0, stream>>>(W_hh, WhhP, NHID);
  k_bias<<<NGATE / 256, 256, 0, stream>>>(b_ih, b_hh, biasP);
  k_hbuf<<<3 * HBUF_DW / 256, 256, 0, stream>>>(hx, hbuf);

  for (int t0 = 0; t0 < NTIME; t0 += Tc) {
    k_gather<<<256, 256, 0, stream>>>(input, emb, Ag, t0, Tc);
    k_gemm<<<dim3(Tc * 64 / 128, NGATE / 128), 256, 0, stream>>>(Ag, WihP, biasP, xproj, Tc * 64);
    k_rec<<<256, 256, 0, stream>>>(WhhP, xproj, hbuf, cbuf, featbuf, cx, seq_len, out, t0, Tc);
  }
  k_fc<<<NBATCH, 256, 0, stream>>>(featbuf, seq_len, fc1W, fc1b, fc2W, fc2b, out);
}

// Round 7
// 2922.610 us; speedup vs baseline: 1.0582x; 1.0582x over previous
//
#include <hip/hip_runtime.h>
#include <stdint.h>

#define NTOK  32000
#define NINP  512
#define NHID  1024
#define NBATCH 64
#define NTIME 512
#define NGATE 4096
#define H3    341   // NHID/3

typedef __attribute__((ext_vector_type(8))) short  short8;
typedef __attribute__((ext_vector_type(4))) float  floatx4;
typedef unsigned long long ull;

#define HBUF_DW (NBATCH * NHID / 2)  // 32768 dwords per h buffer

__device__ __forceinline__ unsigned short f2bf(float f) {
  union { float f; unsigned u; } v; v.f = f;
  unsigned r = v.u + 0x7fffu + ((v.u >> 16) & 1u);
  return (unsigned short)(r >> 16);
}
__device__ __forceinline__ float bf2f(unsigned short h) {
  union { unsigned u; float f; } v; v.u = ((unsigned)h) << 16;
  return v.f;
}

// packed col p -> original gate row g = q*NHID + u
// p = cb*64 + w*16 + uu*4 + q ; u = cb*16 + w*4 + uu   (cb in [0,64), w in [0,4), uu in [0,4))
__device__ __forceinline__ int pack2gate(int p) {
  int cb = p >> 6, r6 = p & 63;
  int w = r6 >> 4, r4 = r6 & 15;
  int uu = r4 >> 2, q = r4 & 3;
  int u = cb * 16 + w * 4 + uu;
  return q * NHID + u;
}

// ---------------- prep kernels ----------------

__global__ void k_pack_w(const float* __restrict__ src, unsigned short* __restrict__ dst, int K) {
  int p = blockIdx.x;
  int g = pack2gate(p);
  const float* s = src + (size_t)g * K;
  unsigned short* d = dst + (size_t)p * K;
  for (int k = threadIdx.x * 2; k < K; k += 512) {
    d[k] = f2bf(s[k]);
    d[k + 1] = f2bf(s[k + 1]);
  }
}

__global__ void k_bias(const float* __restrict__ bih, const float* __restrict__ bhh,
                       float* __restrict__ bp) {
  int p = blockIdx.x * 256 + threadIdx.x;
  if (p < NGATE) { int g = pack2gate(p); bp[p] = bih[g] + bhh[g]; }
}

// pack hx into h buffer 0 (no tags; flag barrier provides ordering)
__global__ void k_hbuf(const float* __restrict__ hx, unsigned* __restrict__ hb) {
  int d = blockIdx.x * 256 + threadIdx.x;
  if (d < HBUF_DW)
    hb[d] = (unsigned)f2bf(hx[2 * d]) | ((unsigned)f2bf(hx[2 * d + 1]) << 16);
}

// gather embeddings for one chunk: Ag[row][k] bf16, row = tl*64 + b
__global__ void k_gather(const int* __restrict__ input, const float* __restrict__ emb,
                         unsigned short* __restrict__ Ag, int t0, int Tc) {
  int total = Tc * 64 * (NINP / 8);
  for (int ci = blockIdx.x * 256 + threadIdx.x; ci < total; ci += gridDim.x * 256) {
    int row = ci >> 6;
    int k8 = (ci & 63) * 8;
    int b = row & 63;
    int tl = row >> 6;
    int tok = input[(size_t)b * NTIME + t0 + tl];
    const float* s = emb + (size_t)tok * NINP + k8;
    unsigned short* d = Ag + (size_t)row * NINP + k8;
#pragma unroll
    for (int j = 0; j < 8; ++j) d[j] = f2bf(s[j]);
  }
}

// ---------------- x_proj GEMM: [M,512] x [4096,512]^T -> bf16 [M,4096] (+bias) ----------------

__global__ __launch_bounds__(256) void k_gemm(const unsigned short* __restrict__ Ag,
                                              const unsigned short* __restrict__ Wp,
                                              const float* __restrict__ biasP,
                                              unsigned short* __restrict__ xproj, int M) {
  __shared__ __attribute__((aligned(16))) unsigned short As[128 * 64];
  __shared__ __attribute__((aligned(16))) unsigned short Bs[128 * 64];
  const int tid = threadIdx.x;
  const int lane = tid & 63;
  const int w = tid >> 6;
  const int wr = w >> 1, wc = w & 1;
  const size_t rowbase = (size_t)blockIdx.x * 128;
  const int pbase = blockIdx.y * 128;

  floatx4 z = {0.f, 0.f, 0.f, 0.f};
  floatx4 acc[4][4];
#pragma unroll
  for (int i = 0; i < 4; ++i)
#pragma unroll
    for (int j = 0; j < 4; ++j) acc[i][j] = z;

  for (int kk = 0; kk < NINP; kk += 64) {
    // stage 128x64 bf16 tiles (XOR-swizzled rows: byte ^= (row&7)<<4)
#pragma unroll
    for (int j = 0; j < 4; ++j) {
      int ci = j * 256 + tid;
      int r = ci >> 3;
      int kb = (ci & 7) * 16;
      int dst = r * 128 + (kb ^ ((r & 7) << 4));
      *(short8*)((char*)As + dst) =
          *(const short8*)((const char*)Ag + ((rowbase + r) * NINP + kk) * 2 + kb);
      *(short8*)((char*)Bs + dst) =
          *(const short8*)((const char*)Wp + ((size_t)(pbase + r) * NINP + kk) * 2 + kb);
    }
    __syncthreads();
#pragma unroll
    for (int k32 = 0; k32 < 2; ++k32) {
      short8 af[4], bfr[4];
      int kq = k32 * 64 + (lane >> 4) * 16;
#pragma unroll
      for (int t = 0; t < 4; ++t) {
        int r = wr * 64 + t * 16 + (lane & 15);
        af[t] = *(const short8*)((const char*)As + r * 128 + (kq ^ ((r & 7) << 4)));
        int cc = wc * 64 + t * 16 + (lane & 15);
        bfr[t] = *(const short8*)((const char*)Bs + cc * 128 + (kq ^ ((cc & 7) << 4)));
      }
#pragma unroll
      for (int tm = 0; tm < 4; ++tm)
#pragma unroll
        for (int tn = 0; tn < 4; ++tn)
          acc[tm][tn] = __builtin_amdgcn_mfma_f32_16x16x32_bf16(af[tm], bfr[tn], acc[tm][tn], 0, 0, 0);
    }
    __syncthreads();
  }
  // epilogue: D row=(lane>>4)*4+j, col=lane&15
#pragma unroll
  for (int tn = 0; tn < 4; ++tn) {
    int p = pbase + wc * 64 + tn * 16 + (lane & 15);
    float bv = biasP[p];
#pragma unroll
    for (int tm = 0; tm < 4; ++tm) {
      size_t r0 = rowbase + wr * 64 + tm * 16 + ((lane >> 4) * 4);
#pragma unroll
      for (int j = 0; j < 4; ++j)
        xproj[(r0 + j) * NGATE + p] = f2bf(acc[tm][tn][j] + bv);
    }
  }
}

// ---------------- persistent LSTM recurrence ----------------
// 256 blocks x 256 thr. rg = bid&3 (16 batch rows), cb = bid>>2 (64 packed cols
// = 16 units x 4 gates). Full 16-row MFMA (no pad waste). Weights in 128 VGPRs.
// Sync per step: per-WAVE flag slots (own 64B line). Wave drains its stores
// (vmcnt0), posts flag; consumer wave w polls all 64 blocks' wave-w flags with
// its 64 lanes. Two syncthreads/step.

__global__ __launch_bounds__(256, 1) void k_rec(const unsigned short* __restrict__ Whp,
                                                const unsigned short* __restrict__ xproj,
                                                unsigned* __restrict__ hbuf,
                                                float* __restrict__ cbuf,
                                                float* __restrict__ featbuf,
                                                const float* __restrict__ cx_in,
                                                const int* __restrict__ seq_len,
                                                float* __restrict__ out,
                                                unsigned* __restrict__ flags, int t0, int Tc) {
  __shared__ __attribute__((aligned(16))) unsigned short hs[16 * NHID];  // 32KB swizzled
  __shared__ __attribute__((aligned(16))) unsigned short xs[16 * 64];    // 2KB
  __shared__ __attribute__((aligned(16))) float gs[4][16][16];           // 4KB

  const int tid = threadIdx.x;
  const int lane = tid & 63;
  const int w = tid >> 6;
  const int rg = blockIdx.x & 3;
  const int cb = blockIdx.x >> 2;
  const int colbase = cb * 64 + w * 16;

  // persistent weight fragments: wave covers 16 packed cols, full K=1024 -> 128 VGPRs
  short8 wf[32];
  {
    const int c0 = lane & 15;
    const int ke = (lane >> 4) * 8;
#pragma unroll
    for (int i = 0; i < 32; ++i)
      wf[i] = *(const short8*)(Whp + (size_t)(colbase + c0) * NHID + i * 32 + ke);
  }

  const int urow = lane >> 2;  // 0..15
  const int uu = lane & 3;     // 0..3
  const int row_g = rg * 16 + urow;
  const int u_g = cb * 16 + w * 4 + uu;
  float c = (t0 == 0) ? cx_in[row_g * NHID + u_g] : cbuf[row_g * NHID + u_g];
  float feat = (t0 == 0) ? 0.f : featbuf[row_g * NHID + u_g];
  const int sl = seq_len[row_g];

  // prefetch xproj slice for tl=0 (stagers: tid<128; 16 rows x 128B)
  short8 xreg;
  if (tid < 128) {
    int r = tid >> 3;
    int kb = (tid & 7) * 16;
    xreg = *(const short8*)((const char*)xproj +
                            ((size_t)(rg * 16 + r) * NGATE + cb * 64) * 2 + kb);
  }

  for (int tl = 0; tl < Tc; ++tl) {
    const int tglob = t0 + tl;
    const ull* hsrc =
        (const ull*)(hbuf + (size_t)(tglob & 1) * HBUF_DW + (size_t)rg * 16 * (NHID / 2));

    // stage h (16 rows x 1024 bf16, 32KB): 16x 8B relaxed-agent loads/thread
    ull vv[16];
#pragma unroll
    for (int j = 0; j < 16; ++j)
      vv[j] = __hip_atomic_load(hsrc + j * 256 + tid, __ATOMIC_RELAXED,
                                __HIP_MEMORY_SCOPE_AGENT);
    // write current step's x slice (prefetched last iter) into LDS
    if (tid < 128) {
      int r = tid >> 3;
      int kb = (tid & 7) * 16;
      *(short8*)((char*)xs + r * 128 + kb) = xreg;
    }
#pragma unroll
    for (int j = 0; j < 16; ++j) {
      int ci = j * 256 + tid;    // 8B-unit index, 0..4095
      int r = ci >> 8;           // row 0..15 (256 ull per row)
      int kb8 = (ci & 255) * 8;  // byte offset in row
      *(ull*)((char*)hs + r * 2048 + (kb8 ^ ((r & 7) << 4))) = vv[j];
    }
    __syncthreads();

    // prefetch next step's x slice (independent; hides under MFMA)
    if (tid < 128 && tl + 1 < Tc) {
      int r = tid >> 3;
      int kb = (tid & 7) * 16;
      xreg = *(const short8*)((const char*)xproj +
                              ((size_t)((tl + 1) * 64 + rg * 16 + r) * NGATE + cb * 64) * 2 + kb);
    }

    // gates[16 rows x 16 cols] = h @ Whp^T, fp32 accum, 4 independent chains
    floatx4 acA = {0.f, 0.f, 0.f, 0.f}, acB = {0.f, 0.f, 0.f, 0.f};
    floatx4 acC = {0.f, 0.f, 0.f, 0.f}, acD = {0.f, 0.f, 0.f, 0.f};
    {
      const int rr = lane & 15;
      const int kq = (lane >> 4) * 16;
      const char* hrow = (const char*)hs + rr * 2048;
      const int sw = (rr & 7) << 4;
#pragma unroll
      for (int kk = 0; kk < 32; kk += 4) {
        short8 a0 = *(const short8*)(hrow + (((kk + 0) * 64 + kq) ^ sw));
        short8 a1 = *(const short8*)(hrow + (((kk + 1) * 64 + kq) ^ sw));
        short8 a2 = *(const short8*)(hrow + (((kk + 2) * 64 + kq) ^ sw));
        short8 a3 = *(const short8*)(hrow + (((kk + 3) * 64 + kq) ^ sw));
        acA = __builtin_amdgcn_mfma_f32_16x16x32_bf16(a0, wf[kk + 0], acA, 0, 0, 0);
        acB = __builtin_amdgcn_mfma_f32_16x16x32_bf16(a1, wf[kk + 1], acB, 0, 0, 0);
        acC = __builtin_amdgcn_mfma_f32_16x16x32_bf16(a2, wf[kk + 2], acC, 0, 0, 0);
        acD = __builtin_amdgcn_mfma_f32_16x16x32_bf16(a3, wf[kk + 3], acD, 0, 0, 0);
      }
    }
    floatx4 acc = (acA + acB) + (acC + acD);

    // add x_proj, dump gates to per-wave LDS (all lanes valid)
    {
      int c0 = lane & 15;
      int quad = lane >> 4;
      floatx4 g;
#pragma unroll
      for (int j = 0; j < 4; ++j)
        g[j] = acc[j] + bf2f(xs[(quad * 4 + j) * 64 + w * 16 + c0]);
      *(floatx4*)&gs[w][c0][quad * 4] = g;
    }
    // same-wave in-order DS: reads below see writes above

    // LSTM update: one (row,unit) per thread
    float gi = gs[w][uu * 4 + 0][urow];
    float gf = gs[w][uu * 4 + 1][urow];
    float gg = gs[w][uu * 4 + 2][urow];
    float go = gs[w][uu * 4 + 3][urow];
    float si = 1.f / (1.f + __expf(-gi));
    float sf = 1.f / (1.f + __expf(-gf));
    float tg = tanhf(gg);
    float so = 1.f / (1.f + __expf(-go));
    c = sf * c + si * tg;
    float h = so * tanhf(c);
    if (tglob < sl) feat += h;

    // paired-lane packed h store (even uu lane stores dword), relaxed agent
    {
      unsigned hb = (unsigned)f2bf(h);
      unsigned partner = (unsigned)__shfl_xor((int)hb, 1);
      if ((lane & 1) == 0) {
        unsigned packed = hb | (partner << 16);
        unsigned* dst = hbuf + (size_t)((tglob + 1) & 1) * HBUF_DW +
                        ((row_g * NHID + u_g) >> 1);
        __hip_atomic_store(dst, packed, __ATOMIC_RELAXED, __HIP_MEMORY_SCOPE_AGENT);
      }
    }
    if (tglob == NTIME - 1) out[128 + row_g * NHID + u_g] = h;

    // per-wave flag barrier: drain own stores, post wave flag, poll 64 blocks
    asm volatile("s_waitcnt vmcnt(0)" ::: "memory");
    unsigned target = (unsigned)(tglob + 1);
    if (lane == 0)
      __hip_atomic_store(flags + ((size_t)(rg * 64 + cb) * 4 + w) * 16, target,
                         __ATOMIC_RELAXED, __HIP_MEMORY_SCOPE_AGENT);
    {
      const unsigned* slot = flags + ((size_t)(rg * 64 + lane) * 4 + w) * 16;
      unsigned v = __hip_atomic_load(slot, __ATOMIC_RELAXED, __HIP_MEMORY_SCOPE_AGENT);
      while (__any(v < target)) {
        __builtin_amdgcn_s_sleep(1);
        v = __hip_atomic_load(slot, __ATOMIC_RELAXED, __HIP_MEMORY_SCOPE_AGENT);
      }
    }
    __syncthreads();
  }

  cbuf[row_g * NHID + u_g] = c;
  featbuf[row_g * NHID + u_g] = feat;
  if (t0 + Tc == NTIME) out[128 + NBATCH * NHID + row_g * NHID + u_g] = c;
}

// ---------------- final FCs + log_softmax ----------------

__global__ void k_fc(const float* __restrict__ feat, const int* __restrict__ seq_len,
                     const float* __restrict__ w1, const float* __restrict__ b1,
                     const float* __restrict__ w2, const float* __restrict__ b2,
                     float* __restrict__ out) {
  int b = blockIdx.x;
  int tid = threadIdx.x;
  __shared__ float fs[NHID];
  __shared__ float x1s[H3 + 3];
  float inv = 1.f / (float)seq_len[b];
  for (int i = tid; i < NHID; i += 256) fs[i] = feat[(size_t)b * NHID + i] * inv;
  __syncthreads();
  for (int j = tid; j < H3; j += 256) {
    const float* wr = w1 + (size_t)j * NHID;
    float s = b1[j];
    for (int k = 0; k < NHID; k += 4)
      s += fs[k] * wr[k] + fs[k + 1] * wr[k + 1] + fs[k + 2] * wr[k + 2] + fs[k + 3] * wr[k + 3];
    x1s[j] = s;
  }
  __syncthreads();
  if (tid == 0) {
    float l0 = b2[0], l1 = b2[1];
    for (int k = 0; k < H3; ++k) {
      l0 += w2[k] * x1s[k];
      l1 += w2[H3 + k] * x1s[k];
    }
    float m = fmaxf(l0, l1);
    float lse = m + logf(__expf(l0 - m) + __expf(l1 - m));
    out[b * 2 + 0] = l0 - lse;
    out[b * 2 + 1] = l1 - lse;
  }
}

// ---------------- host ----------------

extern "C" void kernel_launch(void* const* d_in, const int* in_sizes, int n_in, void* d_out,
                              int out_size, void* d_ws, size_t ws_size, hipStream_t stream) {
  const int* input = (const int*)d_in[0];
  const float* hx = (const float*)d_in[1];
  const float* cx = (const float*)d_in[2];
  const int* seq_len = (const int*)d_in[3];
  const float* emb = (const float*)d_in[4];
  const float* W_ih = (const float*)d_in[5];
  const float* W_hh = (const float*)d_in[6];
  const float* b_ih = (const float*)d_in[7];
  const float* b_hh = (const float*)d_in[8];
  const float* fc1W = (const float*)d_in[9];
  const float* fc1b = (const float*)d_in[10];
  const float* fc2W = (const float*)d_in[11];
  const float* fc2b = (const float*)d_in[12];
  float* out = (float*)d_out;

  char* ws = (char*)d_ws;
  size_t off = 0;
  auto take = [&](size_t n) {
    char* p = ws + off;
    off = (off + n + 255) & ~(size_t)255;
    return p;
  };
  unsigned short* WihP = (unsigned short*)take((size_t)NGATE * NINP * 2);
  unsigned short* WhhP = (unsigned short*)take((size_t)NGATE * NHID * 2);
  float* biasP = (float*)take(NGATE * 4);
  unsigned* hbuf = (unsigned*)take((size_t)2 * HBUF_DW * 4);
  float* cbuf = (float*)take((size_t)NBATCH * NHID * 4);
  float* featbuf = (float*)take((size_t)NBATCH * NHID * 4);
  unsigned* flags = (unsigned*)take((size_t)4 * 64 * 4 * 16 * 4);  // 64KB
  size_t fixed = off;

  int Tc = 512;
  while (Tc > 8) {
    size_t need = fixed + ((size_t)Tc * 64 * NINP * 2 + 256) + ((size_t)Tc * 64 * NGATE * 2 + 256);
    if (need <= ws_size) break;
    Tc >>= 1;
  }
  unsigned short* Ag = (unsigned short*)take((size_t)Tc * 64 * NINP * 2);
  unsigned short* xproj = (unsigned short*)take((size_t)Tc * 64 * NGATE * 2);

  k_pack_w<<<NGATE, 256, 0, stream>>>(W_ih, WihP, NINP);
  k_pack_w<<<NGATE, 256, 0, stream>>>(W_hh, WhhP, NHID);
  k_bias<<<NGATE / 256, 256, 0, stream>>>(b_ih, b_hh, biasP);
  k_hbuf<<<HBUF_DW / 256, 256, 0, stream>>>(hx, hbuf);
  hipMemsetAsync(flags, 0, (size_t)4 * 64 * 4 * 16 * 4, stream);

  for (int t0 = 0; t0 < NTIME; t0 += Tc) {
    k_gather<<<256, 256, 0, stream>>>(input, emb, Ag, t0, Tc);
    k_gemm<<<dim3(Tc * 64 / 128, NGATE / 128), 256, 0, stream>>>(Ag, WihP, biasP, xproj, Tc * 64);
    k_rec<<<256, 256, 0, stream>>>(WhhP, xproj, hbuf, cbuf, featbuf, cx, seq_len, out, flags, t0, Tc);
  }
  k_fc<<<NBATCH, 256, 0, stream>>>(featbuf, seq_len, fc1W, fc1b, fc2W, fc2b, out);
}

// Round 9
// 2081.563 us; speedup vs baseline: 1.4857x; 1.4040x over previous
//
#include <hip/hip_runtime.h>
#include <stdint.h>

#define NTOK  32000
#define NINP  512
#define NHID  1024
#define NBATCH 64
#define NTIME 512
#define NGATE 4096
#define H3    341   // NHID/3

typedef __attribute__((ext_vector_type(8))) short  short8;
typedef __attribute__((ext_vector_type(4))) float  floatx4;
typedef unsigned long long ull;

#define HBUF_DW (NBATCH * NHID / 2)  // 32768 dwords per h buffer

__device__ __forceinline__ unsigned short f2bf(float f) {
  union { float f; unsigned u; } v; v.f = f;
  unsigned r = v.u + 0x7fffu + ((v.u >> 16) & 1u);
  return (unsigned short)(r >> 16);
}
__device__ __forceinline__ float bf2f(unsigned short h) {
  union { unsigned u; float f; } v; v.u = ((unsigned)h) << 16;
  return v.f;
}

// packed col p -> original gate row g = q*NHID + u
// p = cb*128 + w*32 + uu*4 + q ; u = cb*32 + w*8 + uu
__device__ __forceinline__ int pack2gate(int p) {
  int cb = p >> 7, r7 = p & 127;
  int w = r7 >> 5, r5 = r7 & 31;
  int uu = r5 >> 2, q = r5 & 3;
  int u = cb * 32 + w * 8 + uu;
  return q * NHID + u;
}

// ---------------- prep kernels ----------------

__global__ void k_pack_w(const float* __restrict__ src, unsigned short* __restrict__ dst, int K) {
  int p = blockIdx.x;
  int g = pack2gate(p);
  const float* s = src + (size_t)g * K;
  unsigned short* d = dst + (size_t)p * K;
  for (int k = threadIdx.x * 2; k < K; k += 512) {
    d[k] = f2bf(s[k]);
    d[k + 1] = f2bf(s[k + 1]);
  }
}

__global__ void k_bias(const float* __restrict__ bih, const float* __restrict__ bhh,
                       float* __restrict__ bp) {
  int p = blockIdx.x * 256 + threadIdx.x;
  if (p < NGATE) { int g = pack2gate(p); bp[p] = bih[g] + bhh[g]; }
}

__global__ void k_hbuf(const float* __restrict__ hx, unsigned short* __restrict__ hbuf) {
  int i = blockIdx.x * 256 + threadIdx.x;
  if (i < NBATCH * NHID) hbuf[i] = f2bf(hx[i]);
}

// gather embeddings for one chunk: Ag[row][k] bf16, row = tl*64 + b
__global__ void k_gather(const int* __restrict__ input, const float* __restrict__ emb,
                         unsigned short* __restrict__ Ag, int t0, int Tc) {
  int total = Tc * 64 * (NINP / 8);
  for (int ci = blockIdx.x * 256 + threadIdx.x; ci < total; ci += gridDim.x * 256) {
    int row = ci >> 6;
    int k8 = (ci & 63) * 8;
    int b = row & 63;
    int tl = row >> 6;
    int tok = input[(size_t)b * NTIME + t0 + tl];
    const float* s = emb + (size_t)tok * NINP + k8;
    unsigned short* d = Ag + (size_t)row * NINP + k8;
#pragma unroll
    for (int j = 0; j < 8; ++j) d[j] = f2bf(s[j]);
  }
}

// ---------------- x_proj GEMM: [M,512] x [4096,512]^T -> bf16 [M,4096] (+bias) ----------------

__global__ __launch_bounds__(256) void k_gemm(const unsigned short* __restrict__ Ag,
                                              const unsigned short* __restrict__ Wp,
                                              const float* __restrict__ biasP,
                                              unsigned short* __restrict__ xproj, int M) {
  __shared__ __attribute__((aligned(16))) unsigned short As[128 * 64];
  __shared__ __attribute__((aligned(16))) unsigned short Bs[128 * 64];
  const int tid = threadIdx.x;
  const int lane = tid & 63;
  const int w = tid >> 6;
  const int wr = w >> 1, wc = w & 1;
  const size_t rowbase = (size_t)blockIdx.x * 128;
  const int pbase = blockIdx.y * 128;

  floatx4 z = {0.f, 0.f, 0.f, 0.f};
  floatx4 acc[4][4];
#pragma unroll
  for (int i = 0; i < 4; ++i)
#pragma unroll
    for (int j = 0; j < 4; ++j) acc[i][j] = z;

  for (int kk = 0; kk < NINP; kk += 64) {
#pragma unroll
    for (int j = 0; j < 4; ++j) {
      int ci = j * 256 + tid;
      int r = ci >> 3;
      int kb = (ci & 7) * 16;
      int dst = r * 128 + (kb ^ ((r & 7) << 4));
      *(short8*)((char*)As + dst) =
          *(const short8*)((const char*)Ag + ((rowbase + r) * NINP + kk) * 2 + kb);
      *(short8*)((char*)Bs + dst) =
          *(const short8*)((const char*)Wp + ((size_t)(pbase + r) * NINP + kk) * 2 + kb);
    }
    __syncthreads();
#pragma unroll
    for (int k32 = 0; k32 < 2; ++k32) {
      short8 af[4], bfr[4];
      int kq = k32 * 64 + (lane >> 4) * 16;
#pragma unroll
      for (int t = 0; t < 4; ++t) {
        int r = wr * 64 + t * 16 + (lane & 15);
        af[t] = *(const short8*)((const char*)As + r * 128 + (kq ^ ((r & 7) << 4)));
        int cc = wc * 64 + t * 16 + (lane & 15);
        bfr[t] = *(const short8*)((const char*)Bs + cc * 128 + (kq ^ ((cc & 7) << 4)));
      }
#pragma unroll
      for (int tm = 0; tm < 4; ++tm)
#pragma unroll
        for (int tn = 0; tn < 4; ++tn)
          acc[tm][tn] = __builtin_amdgcn_mfma_f32_16x16x32_bf16(af[tm], bfr[tn], acc[tm][tn], 0, 0, 0);
    }
    __syncthreads();
  }
#pragma unroll
  for (int tn = 0; tn < 4; ++tn) {
    int p = pbase + wc * 64 + tn * 16 + (lane & 15);
    float bv = biasP[p];
#pragma unroll
    for (int tm = 0; tm < 4; ++tm) {
      size_t r0 = rowbase + wr * 64 + tm * 16 + ((lane >> 4) * 4);
#pragma unroll
      for (int j = 0; j < 4; ++j)
        xproj[(r0 + j) * NGATE + p] = f2bf(acc[tm][tn][j] + bv);
    }
  }
}

// ---------------- persistent LSTM recurrence ----------------
// 256 blocks x 256 thr: rg = bid&7 (8 batch rows), cb = bid>>3 (128 packed cols).
// Weights register-resident. Sync (all agent-scope, R4-proven protocol):
// h stores (relaxed agent 4B packed) -> vmcnt(0) -> syncthreads -> per-block
// flag (4B, one 128B line per rowgroup) -> all-wave busy poll of the line.
// h staged via 16B sc1 (agent) loads. Two syncthreads per step.

__global__ __launch_bounds__(256, 1) void k_rec(const unsigned short* __restrict__ Whp,
                                                const unsigned short* __restrict__ xproj,
                                                unsigned* __restrict__ hbuf,
                                                float* __restrict__ cbuf,
                                                float* __restrict__ featbuf,
                                                const float* __restrict__ cx_in,
                                                const int* __restrict__ seq_len,
                                                float* __restrict__ out,
                                                unsigned* __restrict__ flags, int t0, int Tc) {
  __shared__ __attribute__((aligned(16))) unsigned short hs[16 * NHID];  // 32KB swizzled
  __shared__ __attribute__((aligned(16))) unsigned short xs[8 * 128];    // 2KB
  __shared__ __attribute__((aligned(16))) float gs[4][32][8];            // 4KB

  const int tid = threadIdx.x;
  const int lane = tid & 63;
  const int w = tid >> 6;
  const int rg = blockIdx.x & 7;
  const int cb = blockIdx.x >> 3;
  const int colbase = cb * 128 + w * 32;

  // zero the pad rows 8..15 of hs once (content of rows 8-15 is ignored but
  // keep deterministic)
  {
    short8 zz = {0, 0, 0, 0, 0, 0, 0, 0};
    short8* zp = (short8*)(hs + 8 * NHID);
    for (int i = tid; i < 1024; i += 256) zp[i] = zz;
  }

  // persistent weight fragments: wave covers 32 packed cols, full K=1024
  short8 wf[64];
  {
    const int c0 = lane & 15;
    const int ke = (lane >> 4) * 8;
#pragma unroll
    for (int i = 0; i < 64; ++i) {
      int kk = i >> 1, n = i & 1;
      wf[i] = *(const short8*)(Whp + (size_t)(colbase + n * 16 + c0) * NHID + kk * 32 + ke);
    }
  }

  const int urow = lane >> 3;  // 0..7
  const int uu = lane & 7;     // 0..7
  const int row_g = rg * 8 + urow;
  const int u_g = cb * 32 + w * 8 + uu;
  float c = (t0 == 0) ? cx_in[row_g * NHID + u_g] : cbuf[row_g * NHID + u_g];
  float feat = (t0 == 0) ? 0.f : featbuf[row_g * NHID + u_g];
  const int sl = seq_len[row_g];
  const bool self = ((lane & 31) == cb);  // own-block flag slot: skip polling it

  // prefetch xproj slice for tl=0 into regs (stager: tid<128)
  short8 xreg;
  if (tid < 128) {
    int r = tid >> 4;
    int kb = (tid & 15) * 16;
    xreg = *(const short8*)((const char*)xproj +
                            ((size_t)(rg * 8 + r) * NGATE + cb * 128) * 2 + kb);
  }

  for (int tl = 0; tl < Tc; ++tl) {
    const int tglob = t0 + tl;
    // dword-unit arithmetic on unsigned* base, THEN cast (R5 lesson)
    const short8* hp =
        (const short8*)(hbuf + (size_t)(tglob & 1) * HBUF_DW + (size_t)rg * 8 * (NHID / 2));

    // write current step's x slice (prefetched last iter) into LDS
    if (tid < 128) {
      int r = tid >> 4;
      int kb = (tid & 15) * 16;
      *(short8*)((char*)xs + r * 256 + kb) = xreg;
    }

    // stage h (8 rows x 1024 bf16, 16KB): 4x16B agent(sc1) loads per thread
    {
      short8 q0, q1, q2, q3;
      asm volatile(
          "global_load_dwordx4 %0, %4, off sc1\n\t"
          "global_load_dwordx4 %1, %5, off sc1\n\t"
          "global_load_dwordx4 %2, %6, off sc1\n\t"
          "global_load_dwordx4 %3, %7, off sc1\n\t"
          "s_waitcnt vmcnt(0)"
          : "=&v"(q0), "=&v"(q1), "=&v"(q2), "=&v"(q3)
          : "v"(hp + tid), "v"(hp + 256 + tid), "v"(hp + 512 + tid), "v"(hp + 768 + tid)
          : "memory");
      int ci, r, kb;
      ci = tid;       r = ci >> 7; kb = (ci & 127) * 16;
      *(short8*)((char*)hs + r * 2048 + (kb ^ ((r & 7) << 4))) = q0;
      ci = 256 + tid; r = ci >> 7; kb = (ci & 127) * 16;
      *(short8*)((char*)hs + r * 2048 + (kb ^ ((r & 7) << 4))) = q1;
      ci = 512 + tid; r = ci >> 7; kb = (ci & 127) * 16;
      *(short8*)((char*)hs + r * 2048 + (kb ^ ((r & 7) << 4))) = q2;
      ci = 768 + tid; r = ci >> 7; kb = (ci & 127) * 16;
      *(short8*)((char*)hs + r * 2048 + (kb ^ ((r & 7) << 4))) = q3;
    }
    __syncthreads();  // (A) hs fully staged

    // prefetch next step's x slice (independent; hides under MFMA)
    if (tid < 128 && tl + 1 < Tc) {
      int r = tid >> 4;
      int kb = (tid & 15) * 16;
      xreg = *(const short8*)((const char*)xproj +
                              ((size_t)((tl + 1) * 64 + rg * 8 + r) * NGATE + cb * 128) * 2 + kb);
    }

    // gates = h @ Whp^T, fp32 accum, 4-acc interleave
    floatx4 acc0a = {0.f, 0.f, 0.f, 0.f}, acc0b = {0.f, 0.f, 0.f, 0.f};
    floatx4 acc1a = {0.f, 0.f, 0.f, 0.f}, acc1b = {0.f, 0.f, 0.f, 0.f};
    {
      const int rr = lane & 15;
      const int kq = (lane >> 4) * 16;
#pragma unroll
      for (int kk = 0; kk < 32; kk += 2) {
        int kb0 = kk * 64 + kq;
        int kb1 = (kk + 1) * 64 + kq;
        short8 a0 = *(const short8*)((const char*)hs + rr * 2048 + (kb0 ^ ((rr & 7) << 4)));
        short8 a1 = *(const short8*)((const char*)hs + rr * 2048 + (kb1 ^ ((rr & 7) << 4)));
        acc0a = __builtin_amdgcn_mfma_f32_16x16x32_bf16(a0, wf[2 * kk + 0], acc0a, 0, 0, 0);
        acc1a = __builtin_amdgcn_mfma_f32_16x16x32_bf16(a0, wf[2 * kk + 1], acc1a, 0, 0, 0);
        acc0b = __builtin_amdgcn_mfma_f32_16x16x32_bf16(a1, wf[2 * kk + 2], acc0b, 0, 0, 0);
        acc1b = __builtin_amdgcn_mfma_f32_16x16x32_bf16(a1, wf[2 * kk + 3], acc1b, 0, 0, 0);
      }
    }
    floatx4 acc0 = acc0a + acc0b;
    floatx4 acc1 = acc1a + acc1b;

    // add x_proj, dump gates to per-wave LDS (valid lanes: rows 0..7)
    if (lane < 32) {
      int r0 = (lane >> 4) * 4;
      int c0 = lane & 15;
      floatx4 g0, g1;
#pragma unroll
      for (int j = 0; j < 4; ++j) {
        g0[j] = acc0[j] + bf2f(xs[(r0 + j) * 128 + w * 32 + c0]);
        g1[j] = acc1[j] + bf2f(xs[(r0 + j) * 128 + w * 32 + c0 + 16]);
      }
      *(floatx4*)&gs[w][c0][r0] = g0;
      *(floatx4*)&gs[w][c0 + 16][r0] = g1;
    }
    // same-wave in-order DS: reads below see writes above

    // LSTM update: one (row,unit) per lane
    float gi = gs[w][uu * 4 + 0][urow];
    float gf = gs[w][uu * 4 + 1][urow];
    float gg = gs[w][uu * 4 + 2][urow];
    float go = gs[w][uu * 4 + 3][urow];
    float si = 1.f / (1.f + __expf(-gi));
    float sf = 1.f / (1.f + __expf(-gf));
    float tg = tanhf(gg);
    float so = 1.f / (1.f + __expf(-go));
    c = sf * c + si * tg;
    float h = so * tanhf(c);
    if (tglob < sl) feat += h;

    // paired-lane packed h store, relaxed agent 4B (fire-and-forget)
    {
      unsigned hb = (unsigned)f2bf(h);
      unsigned partner = (unsigned)__shfl_xor((int)hb, 1);
      if ((lane & 1) == 0) {
        unsigned packed = hb | (partner << 16);
        unsigned* dst = hbuf + (size_t)((tglob + 1) & 1) * HBUF_DW +
                        ((row_g * NHID + u_g) >> 1);
        __hip_atomic_store(dst, packed, __ATOMIC_RELAXED, __HIP_MEMORY_SCOPE_AGENT);
      }
    }
    if (tglob == NTIME - 1) out[128 + row_g * NHID + u_g] = h;

    // barrier: drain own stores, block flag into rowgroup's single 128B line
    asm volatile("s_waitcnt vmcnt(0)" ::: "memory");
    __syncthreads();  // (B) all waves' h stores drained; all xs/hs reads done
    unsigned target = (unsigned)(tglob + 1);
    if (tid == 0)
      __hip_atomic_store(flags + rg * 32 + cb, target, __ATOMIC_RELAXED,
                         __HIP_MEMORY_SCOPE_AGENT);
    // all-wave busy poll: 64 lanes cover the 32-flag line twice (coalesced)
    {
      const unsigned* slot = flags + rg * 32 + (lane & 31);
      unsigned v = self ? 0xFFFFFFFFu
                        : __hip_atomic_load(slot, __ATOMIC_RELAXED, __HIP_MEMORY_SCOPE_AGENT);
      while (__any(v < target)) {
        v = self ? 0xFFFFFFFFu
                 : __hip_atomic_load(slot, __ATOMIC_RELAXED, __HIP_MEMORY_SCOPE_AGENT);
      }
    }
    // no trailing syncthreads needed: (A) of next iter orders hs/xs rewrites
  }

  cbuf[row_g * NHID + u_g] = c;
  featbuf[row_g * NHID + u_g] = feat;
  if (t0 + Tc == NTIME) out[128 + NBATCH * NHID + row_g * NHID + u_g] = c;
}

// ---------------- final FCs + log_softmax ----------------

__global__ void k_fc(const float* __restrict__ feat, const int* __restrict__ seq_len,
                     const float* __restrict__ w1, const float* __restrict__ b1,
                     const float* __restrict__ w2, const float* __restrict__ b2,
                     float* __restrict__ out) {
  int b = blockIdx.x;
  int tid = threadIdx.x;
  __shared__ float fs[NHID];
  __shared__ float x1s[H3 + 3];
  float inv = 1.f / (float)seq_len[b];
  for (int i = tid; i < NHID; i += 256) fs[i] = feat[(size_t)b * NHID + i] * inv;
  __syncthreads();
  for (int j = tid; j < H3; j += 256) {
    const float* wr = w1 + (size_t)j * NHID;
    float s = b1[j];
    for (int k = 0; k < NHID; k += 4)
      s += fs[k] * wr[k] + fs[k + 1] * wr[k + 1] + fs[k + 2] * wr[k + 2] + fs[k + 3] * wr[k + 3];
    x1s[j] = s;
  }
  __syncthreads();
  if (tid == 0) {
    float l0 = b2[0], l1 = b2[1];
    for (int k = 0; k < H3; ++k) {
      l0 += w2[k] * x1s[k];
      l1 += w2[H3 + k] * x1s[k];
    }
    float m = fmaxf(l0, l1);
    float lse = m + logf(__expf(l0 - m) + __expf(l1 - m));
    out[b * 2 + 0] = l0 - lse;
    out[b * 2 + 1] = l1 - lse;
  }
}

// ---------------- host ----------------

extern "C" void kernel_launch(void* const* d_in, const int* in_sizes, int n_in, void* d_out,
                              int out_size, void* d_ws, size_t ws_size, hipStream_t stream) {
  const int* input = (const int*)d_in[0];
  const float* hx = (const float*)d_in[1];
  const float* cx = (const float*)d_in[2];
  const int* seq_len = (const int*)d_in[3];
  const float* emb = (const float*)d_in[4];
  const float* W_ih = (const float*)d_in[5];
  const float* W_hh = (const float*)d_in[6];
  const float* b_ih = (const float*)d_in[7];
  const float* b_hh = (const float*)d_in[8];
  const float* fc1W = (const float*)d_in[9];
  const float* fc1b = (const float*)d_in[10];
  const float* fc2W = (const float*)d_in[11];
  const float* fc2b = (const float*)d_in[12];
  float* out = (float*)d_out;

  char* ws = (char*)d_ws;
  size_t off = 0;
  auto take = [&](size_t n) {
    char* p = ws + off;
    off = (off + n + 255) & ~(size_t)255;
    return p;
  };
  unsigned short* WihP = (unsigned short*)take((size_t)NGATE * NINP * 2);
  unsigned short* WhhP = (unsigned short*)take((size_t)NGATE * NHID * 2);
  float* biasP = (float*)take(NGATE * 4);
  unsigned* hbuf = (unsigned*)take((size_t)2 * HBUF_DW * 4);
  float* cbuf = (float*)take((size_t)NBATCH * NHID * 4);
  float* featbuf = (float*)take((size_t)NBATCH * NHID * 4);
  unsigned* flags = (unsigned*)take(8 * 32 * 4);  // 1KB: one 128B line per rowgroup
  size_t fixed = off;

  int Tc = 512;
  while (Tc > 8) {
    size_t need = fixed + ((size_t)Tc * 64 * NINP * 2 + 256) + ((size_t)Tc * 64 * NGATE * 2 + 256);
    if (need <= ws_size) break;
    Tc >>= 1;
  }
  unsigned short* Ag = (unsigned short*)take((size_t)Tc * 64 * NINP * 2);
  unsigned short* xproj = (unsigned short*)take((size_t)Tc * 64 * NGATE * 2);

  k_pack_w<<<NGATE, 256, 0, stream>>>(W_ih, WihP, NINP);
  k_pack_w<<<NGATE, 256, 0, stream>>>(W_hh, WhhP, NHID);
  k_bias<<<NGATE / 256, 256, 0, stream>>>(b_ih, b_hh, biasP);
  k_hbuf<<<NBATCH * NHID / 256, 256, 0, stream>>>(hx, (unsigned short*)hbuf);
  hipMemsetAsync(flags, 0, 8 * 32 * 4, stream);

  for (int t0 = 0; t0 < NTIME; t0 += Tc) {
    k_gather<<<256, 256, 0, stream>>>(input, emb, Ag, t0, Tc);
    k_gemm<<<dim3(Tc * 64 / 128, NGATE / 128), 256, 0, stream>>>(Ag, WihP, biasP, xproj, Tc * 64);
    k_rec<<<256, 256, 0, stream>>>(WhhP, xproj, hbuf, cbuf, featbuf, cx, seq_len, out, flags, t0, Tc);
  }
  k_fc<<<NBATCH, 256, 0, stream>>>(featbuf, seq_len, fc1W, fc1b, fc2W, fc2b, out);
}